// Round 4
// baseline (296.271 us; speedup 1.0000x reference)
//
#include <hip/hip_runtime.h>

// Problem constants (fixed by the reference setup)
#define NN   32
#define CCH  2
#define PP   (512*512)       // 262144 pixels per image plane
#define RR   (NN*CCH)        // 64 rows
#define NB   512             // distance-quantization buckets over [0,1]
#define CKS  32              // chunk-blocks per image
#define CHUNK (PP/CKS)       // 8192 pixels per chunk
#define HT   512             // threads per block
#define ITERS (CHUNK/(HT*8)) // 2

static_assert(CHUNK % (HT*8) == 0, "");
static_assert(NB == HT || NB*2 == HT || NB == HT*2, "scan assumes NB==HT");
static_assert(CHUNK < 65536, "packed 16-bit cnt would overflow");
static_assert(RR <= 64, "final reduce assumes one wave");

__device__ __forceinline__ double iou_f(double msum, unsigned k, unsigned cs) {
    if (k == 0u) return 0.0;              // "iou before position 1" is 0
    if (msum == 0.0) return 1.0;          // no ones: inter=0, union=k -> iou=1
    const double dk = (double)k, dcs = (double)cs;
    return 1.0 - (msum - dcs) / (msum + dk - dcs);
}

// One fused kernel. Each block: histogram one pixel-chunk of image n for BOTH
// channels (targets read once). Last chunk-block per image (device ticket)
// merges the 32 partials and scans both channels; last image block reduces
// the 64 rows to the final scalar. All integer histogramming -> deterministic.
__global__ __launch_bounds__(HT) void lovasz_fused(
        const float* __restrict__ x, const int* __restrict__ tgt,
        unsigned* g_hist, unsigned* g_pos,
        float* g_row, float* g_valid,
        unsigned* g_tick, float* __restrict__ out)
{
    __shared__ unsigned s_h0[NB];            // 2 KB  (packed cnt<<16 | ones)
    __shared__ unsigned s_h1[NB];            // 2 KB
    __shared__ unsigned s_posr[HT/64][2];
    __shared__ unsigned m_cnt[NB];           // merge phase
    __shared__ unsigned m_ones[NB];
    __shared__ unsigned long long s_scan[HT];
    __shared__ double   s_red[HT/64];
    __shared__ unsigned s_flag;

    const int nb  = blockIdx.x;              // 0 .. NN*CKS-1
    const int n   = nb / CKS, ck = nb % CKS;
    const int tid = threadIdx.x;

    for (int i = tid; i < NB; i += HT) { s_h0[i] = 0u; s_h1[i] = 0u; }
    __syncthreads();

    // ---- phase 1: streaming histogram (both channels, targets once) ----
    const float* x0 = x   + ((size_t)(n*CCH + 0))*PP + (size_t)ck*CHUNK;
    const float* x1 = x   + ((size_t)(n*CCH + 1))*PP + (size_t)ck*CHUNK;
    const int*   tr = tgt + (size_t)n*PP            + (size_t)ck*CHUNK;

    unsigned pos0 = 0, pos1 = 0;
    #pragma unroll
    for (int it = 0; it < ITERS; ++it) {
        const int p = it*(HT*8) + tid*8;
        const float4 a0 = *reinterpret_cast<const float4*>(x0 + p);
        const float4 a1 = *reinterpret_cast<const float4*>(x0 + p + 4);
        const float4 b0 = *reinterpret_cast<const float4*>(x1 + p);
        const float4 b1 = *reinterpret_cast<const float4*>(x1 + p + 4);
        const int4   t0 = *reinterpret_cast<const int4*>(tr + p);
        const int4   t1 = *reinterpret_cast<const int4*>(tr + p + 4);
        const float xs0[8] = {a0.x,a0.y,a0.z,a0.w, a1.x,a1.y,a1.z,a1.w};
        const float xs1[8] = {b0.x,b0.y,b0.z,b0.w, b1.x,b1.y,b1.z,b1.w};
        const int   ts [8] = {t0.x,t0.y,t0.z,t0.w, t1.x,t1.y,t1.z,t1.w};
        #pragma unroll
        for (int j = 0; j < 8; ++j) {
            const unsigned m0 = (ts[j] == 0) ? 1u : 0u;
            const float d0 = m0 ? (1.0f - xs0[j]) : xs0[j];
            int k0 = (int)(d0 * (float)NB); k0 = k0 > NB-1 ? NB-1 : k0;
            atomicAdd(&s_h0[k0], 0x10000u | m0);
            pos0 += (xs0[j] > 0.25f) ? 1u : 0u;

            const unsigned m1 = (ts[j] == 1) ? 1u : 0u;
            const float d1 = m1 ? (1.0f - xs1[j]) : xs1[j];
            int k1 = (int)(d1 * (float)NB); k1 = k1 > NB-1 ? NB-1 : k1;
            atomicAdd(&s_h1[k1], 0x10000u | m1);
            pos1 += (xs1[j] > 0.25f) ? 1u : 0u;
        }
    }

    for (int off = 32; off; off >>= 1) {
        pos0 += __shfl_down(pos0, off);
        pos1 += __shfl_down(pos1, off);
    }
    if ((tid & 63) == 0) { s_posr[tid>>6][0] = pos0; s_posr[tid>>6][1] = pos1; }
    __syncthreads();                       // also completes LDS hist atomics
    if (tid == 0) {
        unsigned p0 = 0, p1 = 0;
        #pragma unroll
        for (int w = 0; w < HT/64; ++w) { p0 += s_posr[w][0]; p1 += s_posr[w][1]; }
        g_pos[nb*2 + 0] = p0; g_pos[nb*2 + 1] = p1;
    }
    const size_t base = (size_t)nb * 2 * NB;
    for (int i = tid; i < NB; i += HT) {
        g_hist[base + i]      = s_h0[i];
        g_hist[base + NB + i] = s_h1[i];
    }

    // ---- ticket: last chunk-block of image n does the merge+scan ----
    __threadfence();                       // release partials device-wide
    if (tid == 0) s_flag = atomicAdd(&g_tick[n], 1u);
    __syncthreads();
    if (s_flag != CKS-1) return;
    __threadfence();                       // acquire: see all 32 partials

    // ---- phase 2: per-channel merge + bucket suffix-scan (NB==HT, Q=1) ----
    for (int c = 0; c < CCH; ++c) {
        for (int i = tid; i < NB; i += HT) {
            unsigned cs = 0, os = 0;
            #pragma unroll
            for (int b = 0; b < CKS; ++b) {
                const unsigned v = g_hist[((size_t)(n*CKS + b)*2 + c)*NB + i];
                cs += v >> 16; os += v & 0xffffu;
            }
            m_cnt[i] = cs; m_ones[i] = os;
        }
        __syncthreads();

        const int bk = NB-1 - tid;         // descending distance, position=tid
        const unsigned lc = m_cnt[bk], lo = m_ones[bk];
        const unsigned long long v =
            ((unsigned long long)lc << 32) | (unsigned long long)lo;
        s_scan[tid] = v;
        __syncthreads();
        for (int off = 1; off < HT; off <<= 1) {
            const unsigned long long add = (tid >= off) ? s_scan[tid-off] : 0ULL;
            __syncthreads();
            s_scan[tid] += add;
            __syncthreads();
        }
        const unsigned long long incl = s_scan[tid];
        const unsigned long long tot  = s_scan[HT-1];
        const unsigned msum = (unsigned)(tot & 0xffffffffULL);
        const unsigned k  = (unsigned)((incl - v) >> 32);
        const unsigned cs = (unsigned)((incl - v) & 0xffffffffULL);

        double acc = 0.0;
        if (lc) {
            const double dmsum = (double)msum;
            const double ip  = iou_f(dmsum, k, cs);
            const double in_ = iou_f(dmsum, k + lc, cs + lo);
            acc = (((double)bk + 0.5) * (1.0/(double)NB)) * (in_ - ip);
        }
        for (int off = 32; off; off >>= 1) acc += __shfl_down(acc, off);
        if ((tid & 63) == 0) s_red[tid>>6] = acc;
        __syncthreads();
        if (tid == 0) {
            double t = 0.0;
            #pragma unroll
            for (int w = 0; w < HT/64; ++w) t += s_red[w];
            unsigned pos = 0;
            for (int b = 0; b < CKS; ++b) pos += g_pos[(n*CKS + b)*2 + c];
            const bool valid = !(msum == 0u && pos == 0u);
            const double W[CCH] = {1.428, 40.097};
            const int r = n*CCH + c;
            g_row[r]   = valid ? (float)(t * W[c]) : 0.f;
            g_valid[r] = valid ? 1.f : 0.f;
        }
        __syncthreads();                   // before reusing m_cnt/s_scan
    }

    // ---- ticket 2: last image reduces the 64 rows to the scalar ----
    __threadfence();
    if (tid == 0) s_flag = atomicAdd(&g_tick[NN], 1u);
    __syncthreads();
    if (s_flag != NN-1) return;
    __threadfence();

    if (tid < 64) {
        const volatile float* vr = g_row;
        const volatile float* vv = g_valid;
        double t  = (tid < RR) ? (double)vr[tid] : 0.0;
        double vl = (tid < RR) ? (double)vv[tid] : 0.0;
        for (int off = 32; off; off >>= 1) {
            t  += __shfl_down(t, off);
            vl += __shfl_down(vl, off);
        }
        if (tid == 0) out[0] = (float)(t / (double)NN / vl);
    }
}

extern "C" void kernel_launch(void* const* d_in, const int* in_sizes, int n_in,
                              void* d_out, int out_size, void* d_ws, size_t ws_size,
                              hipStream_t stream) {
    const float* x   = (const float*)d_in[0];
    const int*   tgt = (const int*)d_in[1];
    float* out = (float*)d_out;

    // workspace layout (tickets first so one tiny memset covers them)
    unsigned* g_tick = (unsigned*)d_ws;                  // 64 u32 (use NN+1)
    unsigned* g_hist = g_tick + 64;                      // NN*CKS*2*NB u32 = 4 MB
    unsigned* g_pos  = g_hist + (size_t)NN*CKS*2*NB;     // NN*CKS*2 u32
    float*    g_row  = (float*)(g_pos + NN*CKS*2);       // RR floats
    float*    g_valid = g_row + RR;                      // RR floats

    hipMemsetAsync(g_tick, 0, 64*sizeof(unsigned), stream);
    lovasz_fused<<<NN*CKS, HT, 0, stream>>>(x, tgt, g_hist, g_pos,
                                            g_row, g_valid, g_tick, out);
}

// Round 5
// 30.906 us; speedup vs baseline: 9.5861x; 9.5861x over previous
//
#include <hip/hip_runtime.h>

// Problem constants (fixed by the reference setup)
#define NN   32
#define CCH  2
#define PP   (512*512)       // 262144 pixels per image plane
#define RR   (NN*CCH)        // 64 rows
#define NB   512             // distance-quantization buckets over [0,1]
#define CKS  32              // chunk-blocks per image
#define CHUNK (PP/CKS)       // 8192 pixels per chunk
#define HT   512             // threads per hist block
#define ST   512             // threads per scan block == NB
#define ITERS (CHUNK/(HT*8)) // 2

static_assert(CHUNK % (HT*8) == 0, "");
static_assert(ST == NB, "scan assumes one bucket per thread");
static_assert(CHUNK < 65536, "packed 16-bit cnt would overflow");
static_assert(RR <= 64, "final reduce assumes one wave");

__device__ __forceinline__ double iou_f(double msum, unsigned k, unsigned cs) {
    if (k == 0u) return 0.0;              // "iou before position 1" is 0
    if (msum == 0.0) return 1.0;          // no ones: inter=0, union=k -> iou=1
    const double dk = (double)k, dcs = (double)cs;
    return 1.0 - (msum - dcs) / (msum + dk - dcs);
}

// Kernel 1: each block histograms one pixel-chunk of image n for BOTH
// channels (targets read once). Packed u32 per bucket: (cnt<<16)|ones.
// One LDS atomic per (pixel,channel). Pure integer -> bit-deterministic.
// No device fences here: the kernel boundary publishes the partials.
__global__ __launch_bounds__(HT) void hist_kernel(
        const float* __restrict__ x, const int* __restrict__ tgt,
        unsigned* __restrict__ g_hist, unsigned* __restrict__ g_pos,
        unsigned* __restrict__ g_ticket)
{
    __shared__ unsigned s_h0[NB];            // 2 KB
    __shared__ unsigned s_h1[NB];            // 2 KB
    __shared__ unsigned s_posr[HT/64][2];

    const int nb  = blockIdx.x;              // 0 .. NN*CKS-1
    const int n   = nb / CKS, ck = nb % CKS;
    const int tid = threadIdx.x;

    if (nb == 0 && tid == 0) *g_ticket = 0u; // scan's ticket (ordered by kernel boundary)

    for (int i = tid; i < NB; i += HT) { s_h0[i] = 0u; s_h1[i] = 0u; }
    __syncthreads();

    const float* x0 = x   + ((size_t)(n*CCH + 0))*PP + (size_t)ck*CHUNK;
    const float* x1 = x   + ((size_t)(n*CCH + 1))*PP + (size_t)ck*CHUNK;
    const int*   tr = tgt + (size_t)n*PP            + (size_t)ck*CHUNK;

    unsigned pos0 = 0, pos1 = 0;
    #pragma unroll
    for (int it = 0; it < ITERS; ++it) {
        const int p = it*(HT*8) + tid*8;
        const float4 a0 = *reinterpret_cast<const float4*>(x0 + p);
        const float4 a1 = *reinterpret_cast<const float4*>(x0 + p + 4);
        const float4 b0 = *reinterpret_cast<const float4*>(x1 + p);
        const float4 b1 = *reinterpret_cast<const float4*>(x1 + p + 4);
        const int4   t0 = *reinterpret_cast<const int4*>(tr + p);
        const int4   t1 = *reinterpret_cast<const int4*>(tr + p + 4);
        const float xs0[8] = {a0.x,a0.y,a0.z,a0.w, a1.x,a1.y,a1.z,a1.w};
        const float xs1[8] = {b0.x,b0.y,b0.z,b0.w, b1.x,b1.y,b1.z,b1.w};
        const int   ts [8] = {t0.x,t0.y,t0.z,t0.w, t1.x,t1.y,t1.z,t1.w};
        #pragma unroll
        for (int j = 0; j < 8; ++j) {
            const unsigned m0 = (ts[j] == 0) ? 1u : 0u;
            const float d0 = m0 ? (1.0f - xs0[j]) : xs0[j];
            int k0 = (int)(d0 * (float)NB); k0 = k0 > NB-1 ? NB-1 : k0;
            atomicAdd(&s_h0[k0], 0x10000u | m0);
            pos0 += (xs0[j] > 0.25f) ? 1u : 0u;

            const unsigned m1 = (ts[j] == 1) ? 1u : 0u;
            const float d1 = m1 ? (1.0f - xs1[j]) : xs1[j];
            int k1 = (int)(d1 * (float)NB); k1 = k1 > NB-1 ? NB-1 : k1;
            atomicAdd(&s_h1[k1], 0x10000u | m1);
            pos1 += (xs1[j] > 0.25f) ? 1u : 0u;
        }
    }

    for (int off = 32; off; off >>= 1) {
        pos0 += __shfl_down(pos0, off);
        pos1 += __shfl_down(pos1, off);
    }
    if ((tid & 63) == 0) { s_posr[tid>>6][0] = pos0; s_posr[tid>>6][1] = pos1; }
    __syncthreads();                       // also completes LDS hist atomics
    if (tid == 0) {
        unsigned p0 = 0, p1 = 0;
        #pragma unroll
        for (int w = 0; w < HT/64; ++w) { p0 += s_posr[w][0]; p1 += s_posr[w][1]; }
        g_pos[nb*2 + 0] = p0; g_pos[nb*2 + 1] = p1;
    }
    const size_t base = (size_t)nb * 2 * NB;
    for (int i = tid; i < NB; i += HT) {
        g_hist[base + i]      = s_h0[i];
        g_hist[base + NB + i] = s_h1[i];
    }
}

// Kernel 2: one block per row (n,c). NB==ST: thread tid owns scan position
// tid (bucket NB-1-tid) -> merge straight into registers, single-element
// Hillis-Steele scan. Last block (ticket) reduces the 64 rows to the scalar.
__global__ __launch_bounds__(ST) void scan_kernel(
        const unsigned* __restrict__ g_hist, const unsigned* __restrict__ g_pos,
        float* __restrict__ g_row, float* __restrict__ g_valid,
        unsigned* __restrict__ g_ticket, float* __restrict__ out)
{
    __shared__ unsigned long long s_scan[ST];
    __shared__ double   s_red[ST/64];
    __shared__ unsigned s_flag;

    const int r = blockIdx.x;
    const int n = r / CCH, c = r % CCH;
    const int tid = threadIdx.x;

    // merge the CKS partials for this row's bucket (fixed order -> deterministic)
    const int bk = NB-1 - tid;             // descending distance, position=tid
    unsigned lc = 0, lo = 0;
    #pragma unroll
    for (int b = 0; b < CKS; ++b) {
        const unsigned v = g_hist[((size_t)(n*CKS + b)*2 + c)*NB + bk];
        lc += v >> 16; lo += v & 0xffffu;
    }

    // packed (cnt<<32 | ones) inclusive Hillis-Steele block scan
    const unsigned long long v =
        ((unsigned long long)lc << 32) | (unsigned long long)lo;
    s_scan[tid] = v;
    __syncthreads();
    for (int off = 1; off < ST; off <<= 1) {
        const unsigned long long add = (tid >= off) ? s_scan[tid-off] : 0ULL;
        __syncthreads();
        s_scan[tid] += add;
        __syncthreads();
    }
    const unsigned long long incl = s_scan[tid];
    const unsigned long long tot  = s_scan[ST-1];
    const unsigned msum = (unsigned)(tot & 0xffffffffULL);
    const unsigned k  = (unsigned)((incl - v) >> 32);
    const unsigned cs = (unsigned)((incl - v) & 0xffffffffULL);

    double acc = 0.0;
    if (lc) {
        const double dmsum = (double)msum;
        const double ip  = iou_f(dmsum, k, cs);
        const double in_ = iou_f(dmsum, k + lc, cs + lo);
        acc = (((double)bk + 0.5) * (1.0/(double)NB)) * (in_ - ip);
    }
    for (int off = 32; off; off >>= 1) acc += __shfl_down(acc, off);
    if ((tid & 63) == 0) s_red[tid>>6] = acc;
    __syncthreads();
    if (tid == 0) {
        double t = 0.0;
        #pragma unroll
        for (int w = 0; w < ST/64; ++w) t += s_red[w];
        unsigned pos = 0;
        for (int b = 0; b < CKS; ++b) pos += g_pos[(n*CKS + b)*2 + c];
        const bool valid = !(msum == 0u && pos == 0u);
        const double W[CCH] = {1.428, 40.097};
        g_row[r]   = valid ? (float)(t * W[c]) : 0.f;
        g_valid[r] = valid ? 1.f : 0.f;
        __threadfence();                   // publish row result device-wide
        s_flag = atomicAdd(g_ticket, 1u);  // device-scope by default
    }
    __syncthreads();

    if (s_flag == RR - 1) {                // last block reduces all rows
        __threadfence();
        if (tid < 64) {
            const volatile float* vr = g_row;
            const volatile float* vv = g_valid;
            double t  = (tid < RR) ? (double)vr[tid] : 0.0;
            double vl = (tid < RR) ? (double)vv[tid] : 0.0;
            for (int off = 32; off; off >>= 1) {
                t  += __shfl_down(t, off);
                vl += __shfl_down(vl, off);
            }
            if (tid == 0) out[0] = (float)(t / (double)NN / vl);
        }
    }
}

extern "C" void kernel_launch(void* const* d_in, const int* in_sizes, int n_in,
                              void* d_out, int out_size, void* d_ws, size_t ws_size,
                              hipStream_t stream) {
    const float* x   = (const float*)d_in[0];
    const int*   tgt = (const int*)d_in[1];
    float* out = (float*)d_out;

    // workspace layout (~4.2 MB, every word written before read -> no memset)
    const size_t SZH = (size_t)NN * CKS * 2 * NB;        // 4 MB of u32
    unsigned* g_hist  = (unsigned*)d_ws;
    unsigned* g_pos   = g_hist + SZH;                    // NN*CKS*2 u32
    float*    g_row   = (float*)(g_pos + NN*CKS*2);      // RR floats
    float*    g_valid = g_row + RR;                      // RR floats
    unsigned* g_ticket = (unsigned*)(g_valid + RR);      // 1 u32

    hist_kernel<<<NN*CKS, HT, 0, stream>>>(x, tgt, g_hist, g_pos, g_ticket);
    scan_kernel<<<RR, ST, 0, stream>>>(g_hist, g_pos, g_row, g_valid, g_ticket, out);
}